// Round 6
// baseline (246.621 us; speedup 1.0000x reference)
//
#include <hip/hip_runtime.h>

typedef __attribute__((ext_vector_type(4))) float f32x4;
typedef __attribute__((ext_vector_type(8))) short short8;

#define DEVI static __device__ __forceinline__

constexpr int B_ = 4;
constexpr int N_ = 4096;
constexpr int H_ = 128;
constexpr size_t ELEMS = (size_t)B_ * N_ * H_;   // per tensor
constexpr size_t TSB = ELEMS * 2;                // bf16 bytes per tensor

// ---- v6 geometry ----
constexpr int QT = 128;                 // q rows per block (4 waves x 32)
constexpr int KVB = 32;                 // kv rows per step (small -> 4 blocks/CU)
constexpr int NTH = 256;                // 4 waves

DEVI unsigned short f2bf(float x) {
  union { float f; unsigned u; } a; a.f = x;
  unsigned u = a.u;
  return (unsigned short)((u + 0x7FFFu + ((u >> 16) & 1u)) >> 16);  // RNE
}

DEVI unsigned cvt_pk_bf16(float lo, float hi) {
  unsigned w;
  asm("v_cvt_pk_bf16_f32 %0, %1, %2" : "=v"(w) : "v"(lo), "v"(hi));
  return w;
}

DEVI int swz(int byteoff, int row) { return byteoff ^ ((row & 7) << 4); }

DEVI void gl_lds16(const void* g, void* l) {
  __builtin_amdgcn_global_load_lds(
      (const __attribute__((address_space(1))) void*)g,
      (__attribute__((address_space(3))) void*)l, 16, 0, 0);
}

// ---------------- pre-pass: convert Q(scaled)/K to bf16 ----------------
__global__ void conv_qk(const float* __restrict__ q, const float* __restrict__ k,
                        unsigned short* __restrict__ qb, unsigned short* __restrict__ kb) {
  const float qscale = 0.08838834764831845f * 1.4426950408889634f;  // 1/sqrt(H)*log2e
  size_t i = (size_t)blockIdx.x * blockDim.x + threadIdx.x;  // vec8 index
  {
    const float4* s = (const float4*)q + 2 * i;
    float4 a = s[0], b = s[1];
    short8 t;
    t[0] = (short)f2bf(a.x * qscale); t[1] = (short)f2bf(a.y * qscale);
    t[2] = (short)f2bf(a.z * qscale); t[3] = (short)f2bf(a.w * qscale);
    t[4] = (short)f2bf(b.x * qscale); t[5] = (short)f2bf(b.y * qscale);
    t[6] = (short)f2bf(b.z * qscale); t[7] = (short)f2bf(b.w * qscale);
    *(short8*)(qb + i * 8) = t;
  }
  {
    const float4* s = (const float4*)k + 2 * i;
    float4 a = s[0], b = s[1];
    short8 t;
    t[0] = (short)f2bf(a.x); t[1] = (short)f2bf(a.y);
    t[2] = (short)f2bf(a.z); t[3] = (short)f2bf(a.w);
    t[4] = (short)f2bf(b.x); t[5] = (short)f2bf(b.y);
    t[6] = (short)f2bf(b.z); t[7] = (short)f2bf(b.w);
    *(short8*)(kb + i * 8) = t;
  }
}

// ---------------- pre-pass: V -> V^T bf16 ([b][h][n]) ----------------
__global__ void conv_vt(const float* __restrict__ v, unsigned short* __restrict__ vt) {
  __shared__ unsigned short T[64][72];
  const int n0 = blockIdx.x * 64, h0 = blockIdx.y * 64, b = blockIdx.z;
  const int t = threadIdx.x;
  const int c4 = t & 15, r = t >> 4;
#pragma unroll
  for (int i = 0; i < 4; ++i) {
    int n = n0 + r + 16 * i;
    float4 val = *(const float4*)(v + ((size_t)b * N_ + n) * H_ + h0 + 4 * c4);
    T[4 * c4 + 0][r + 16 * i] = f2bf(val.x);
    T[4 * c4 + 1][r + 16 * i] = f2bf(val.y);
    T[4 * c4 + 2][r + 16 * i] = f2bf(val.z);
    T[4 * c4 + 3][r + 16 * i] = f2bf(val.w);
  }
  __syncthreads();
  const int c8 = t & 7, hr = t >> 3;
#pragma unroll
  for (int i = 0; i < 2; ++i) {
    int hl = hr + 32 * i;
    short8 val = *(const short8*)(&T[hl][8 * c8]);
    *(short8*)(vt + ((size_t)b * H_ + h0 + hl) * N_ + n0 + 8 * c8) = val;
  }
}

// ---------------- main v6: 4 blocks/CU, XCD-local, defer-max ----------------
template <int KS>
__global__ __launch_bounds__(NTH, 4)
void fattn_v6(const unsigned short* __restrict__ qws,
              const unsigned short* __restrict__ kws,
              const unsigned short* __restrict__ vtws,
              float* __restrict__ opart, float* __restrict__ mlpart) {
  constexpr int KVRANGE = N_ / KS;
  constexpr int NST = KVRANGE / KVB;

  __shared__ __align__(16) char smem[36864];
  char* Kb0 = smem;             // 8KB x2 (double buffer) [32 kv][256B]
  char* Vb0 = smem + 16384;     // 8KB x2                 [128 h][64B]
  // P: per-wave 1KB at smem + 32768 + wave*1024          [16 q][64B]

  const int tid = threadIdx.x, wave = tid >> 6, lane = tid & 63;
  const int l15 = lane & 15, l4 = lane >> 4;

  // XCD-locality decode (bid%8 = xcd): each XCD owns few (b,z) K/V slices.
  const int bid = blockIdx.x;
  int x, b, z;
  if (KS == 4) {               // 512 blocks = 8 xcd * 2 pairs * 32 x
    int pair = (bid & 7) * 2 + ((bid >> 3) & 1);
    x = bid >> 4;
    b = pair >> 2;
    z = pair & 3;
  } else {                     // KS==2: 256 blocks
    int pair = bid & 7;
    x = bid >> 3;
    b = pair >> 1;
    z = pair & 1;
  }

  const int qg0 = x * QT + wave * 32;
  const size_t kvz = (size_t)z * KVRANGE;
  char* Pw = smem + 32768 + wave * 1024;
  const int pswz = (l15 & 3) << 4;

  const unsigned short* qp0 = qws + ((size_t)b * N_ + qg0 + l15) * H_;
  short8 qf0[4], qf1[4];
#pragma unroll
  for (int kc = 0; kc < 4; ++kc) {
    qf0[kc] = *(const short8*)(qp0 + 8 * l4 + 32 * kc);
    qf1[kc] = *(const short8*)(qp0 + 16 * H_ + 8 * l4 + 32 * kc);
  }

  f32x4 O0[8], O1[8];
#pragma unroll
  for (int i = 0; i < 8; ++i) { O0[i] = (f32x4){0,0,0,0}; O1[i] = (f32x4){0,0,0,0}; }
  float m0 = 0.f, l0 = 0.f, m1 = 0.f, l1 = 0.f;  // exp2-domain, defer-max

  const char* kbase = (const char*)(kws + ((size_t)b * N_ + kvz) * H_);
  const char* vbase = (const char*)(vtws + (size_t)b * H_ * N_) + kvz * 2;

  auto stage = [&](int buf, int step) {
    const char* kt = kbase + (size_t)step * KVB * H_ * 2;  // 8KB [32][256B]
    char* kd = Kb0 + buf * 8192;
#pragma unroll
    for (int i = 0; i < 2; ++i) {
      int off = (tid + 256 * i) * 16;
      int row = off >> 8, col = off & 255;
      gl_lds16(kt + row * 256 + (col ^ ((row & 7) << 4)), kd + off);
    }
    const char* vt0 = vbase + (size_t)step * KVB * 2;      // [h][kv], row stride N_*2
    char* vd = Vb0 + buf * 8192;
#pragma unroll
    for (int i = 0; i < 2; ++i) {
      int off = (tid + 256 * i) * 16;
      int h = off >> 6, colb = off & 63;
      gl_lds16(vt0 + (size_t)h * (N_ * 2) + (colb ^ ((h & 3) << 4)), vd + off);
    }
  };

  // defer-max online softmax: p=exp2(S-m); rescale only if maxp>256 (rare)
  auto softmax_prep = [&](f32x4 (&S)[2], float& m, float& l, f32x4 (&O)[8], short8& pf) {
    float p[8];
#pragma unroll
    for (int ct = 0; ct < 2; ++ct)
#pragma unroll
      for (int r = 0; r < 4; ++r)
        p[4 * ct + r] = __builtin_amdgcn_exp2f(S[ct][r] - m);
    float a0 = fmaxf(p[0], p[1]), a1 = fmaxf(p[2], p[3]);
    float a2 = fmaxf(p[4], p[5]), a3 = fmaxf(p[6], p[7]);
    float mx = fmaxf(fmaxf(a0, a1), fmaxf(a2, a3));
    mx = fmaxf(mx, __shfl_xor(mx, 16));
    mx = fmaxf(mx, __shfl_xor(mx, 32));
    float rs = ((p[0] + p[1]) + (p[2] + p[3])) + ((p[4] + p[5]) + (p[6] + p[7]));
    rs += __shfl_xor(rs, 16);
    rs += __shfl_xor(rs, 32);
    if (__builtin_expect(!__all(mx <= 256.f), 0)) {
      float sc = fmaxf(mx, 1.f);
      float ai = 1.f / sc;
      m += __builtin_amdgcn_logf(sc);     // v_log_f32 = log2
      l = (l + rs) * ai;
#pragma unroll
      for (int i = 0; i < 8; ++i) p[i] *= ai;
#pragma unroll
      for (int i = 0; i < 8; ++i) O[i] = O[i] * ai;
    } else {
      l += rs;
    }
    // pack P -> per-wave LDS [16 q][32 kv] -> PV B-frag
#pragma unroll
    for (int ct = 0; ct < 2; ++ct) {
      uint2 pk;
      pk.x = cvt_pk_bf16(p[4 * ct], p[4 * ct + 1]);
      pk.y = cvt_pk_bf16(p[4 * ct + 2], p[4 * ct + 3]);
      *(uint2*)(Pw + ((l15 * 64 + 32 * ct + 8 * l4) ^ pswz)) = pk;
    }
    pf = *(const short8*)(Pw + ((l15 * 64 + 16 * l4) ^ pswz));
  };

  stage(0, 0);
  __syncthreads();
  int cur = 0;

  for (int st = 0; st < NST; ++st) {
    if (st + 1 < NST) stage(cur ^ 1, st + 1);

    const char* Kl = Kb0 + cur * 8192;
    const char* Vl = Vb0 + cur * 8192;

    // ---- QK^T (swapped): S^T[kv32][q32] ----
    f32x4 S0[2], S1[2];
#pragma unroll
    for (int ct = 0; ct < 2; ++ct) { S0[ct] = (f32x4){0,0,0,0}; S1[ct] = (f32x4){0,0,0,0}; }
    __builtin_amdgcn_s_setprio(1);
#pragma unroll
    for (int kc = 0; kc < 4; ++kc) {
#pragma unroll
      for (int ct = 0; ct < 2; ++ct) {
        int kr = 16 * ct + l15;
        short8 af = *(const short8*)(Kl + ((kr * 256 + 16 * l4 + 64 * kc) ^ ((kr & 7) << 4)));
        S0[ct] = __builtin_amdgcn_mfma_f32_16x16x32_bf16(af, qf0[kc], S0[ct], 0, 0, 0);
        S1[ct] = __builtin_amdgcn_mfma_f32_16x16x32_bf16(af, qf1[kc], S1[ct], 0, 0, 0);
      }
    }
    __builtin_amdgcn_s_setprio(0);

    // ---- softmax(S0) -> PV(O0) ; softmax(S1) -> PV(O1): VALU/MFMA overlap ----
    short8 pf0, pf1;
    softmax_prep(S0, m0, l0, O0, pf0);
#pragma unroll
    for (int ct2 = 0; ct2 < 8; ++ct2) {
      int hr = 16 * ct2 + l15;
      short8 vf = *(const short8*)(Vl + ((hr * 64 + 16 * l4) ^ ((hr & 3) << 4)));
      O0[ct2] = __builtin_amdgcn_mfma_f32_16x16x32_bf16(vf, pf0, O0[ct2], 0, 0, 0);
    }
    softmax_prep(S1, m1, l1, O1, pf1);
#pragma unroll
    for (int ct2 = 0; ct2 < 8; ++ct2) {
      int hr = 16 * ct2 + l15;
      short8 vf = *(const short8*)(Vl + ((hr * 64 + 16 * l4) ^ ((hr & 3) << 4)));
      O1[ct2] = __builtin_amdgcn_mfma_f32_16x16x32_bf16(vf, pf1, O1[ct2], 0, 0, 0);
    }

    __syncthreads();
    cur ^= 1;
  }

  // ---- epilogue: direct stores (O^T lane layout is h-contiguous f32x4) ----
  if (l4 == 0) {
    size_t r0 = ((size_t)z * B_ + b) * N_ + qg0 + l15;
    mlpart[2 * r0] = m0;
    mlpart[2 * r0 + 1] = l0;
    mlpart[2 * (r0 + 16)] = m1;
    mlpart[2 * (r0 + 16) + 1] = l1;
  }
  float* od0 = opart + (((size_t)z * B_ + b) * N_ + qg0 + l15) * H_ + 4 * l4;
  float* od1 = od0 + 16 * H_;
#pragma unroll
  for (int ct2 = 0; ct2 < 8; ++ct2) {
    *(f32x4*)(od0 + 16 * ct2) = O0[ct2];
    *(f32x4*)(od1 + 16 * ct2) = O1[ct2];
  }
}

// ---------------- combine the KS kv-split partials ----------------
template <int KS>
__global__ void combine_k(const float* __restrict__ opart, const float* __restrict__ mlpart,
                          float* __restrict__ out) {
  const int t = threadIdx.x;
  size_t row = (size_t)blockIdx.x * 8 + (t >> 5);
  int hc = (t & 31) * 4;
  float mz[KS], lz[KS];
  float mi = -__builtin_inff();
#pragma unroll
  for (int z = 0; z < KS; ++z) {
    size_t r = (size_t)z * B_ * N_ + row;
    mz[z] = mlpart[2 * r];
    lz[z] = mlpart[2 * r + 1];
    mi = fmaxf(mi, mz[z]);
  }
  float lsum = 0.f;
  float az[KS];
#pragma unroll
  for (int z = 0; z < KS; ++z) {
    az[z] = __builtin_amdgcn_exp2f(mz[z] - mi);
    lsum += az[z] * lz[z];
  }
  float rinv = 1.f / lsum;
  f32x4 acc = (f32x4){0, 0, 0, 0};
#pragma unroll
  for (int z = 0; z < KS; ++z) {
    f32x4 oz = *(const f32x4*)(opart + (size_t)z * B_ * N_ * H_ + row * H_ + hc);
    acc = acc + oz * (az[z] * rinv);
  }
  *(f32x4*)(out + row * H_ + hc) = acc;
}

// ================= fallback path (minimal ws) =================
constexpr int FB_QTILE = 64;
constexpr int FB_KVSTEP = 128;
constexpr int FB_KVHALF = 64;
constexpr int FB_NTH = 512;
constexpr int FB_NSTEPS = N_ / FB_KVSTEP;

__global__ __launch_bounds__(FB_NTH, 2)
void fattn_fast(const unsigned short* __restrict__ qws,
                const unsigned short* __restrict__ kws,
                const unsigned short* __restrict__ vtws,
                float* __restrict__ out) {
  __shared__ unsigned short Kbuf[2][FB_KVSTEP * H_];
  __shared__ unsigned short Vbuf[2][H_ * FB_KVSTEP];
  __shared__ unsigned short Plds[8][16 * FB_KVHALF];
  __shared__ float MLlds[4][16][2];

  const int tid = threadIdx.x;
  const int wave = tid >> 6;
  const int lane = tid & 63;
  const int l15 = lane & 15;
  const int l4 = lane >> 4;
  const int sub = wave & 3;
  const int grp = wave >> 2;

  const int b = blockIdx.y;
  const int qbase = blockIdx.x * FB_QTILE;

  const unsigned short* qp = qws + ((size_t)b * N_ + qbase + sub * 16 + l15) * H_;
  short8 qfrag[4];
#pragma unroll
  for (int kc = 0; kc < 4; ++kc)
    qfrag[kc] = *(const short8*)(qp + 8 * l4 + 32 * kc);

  f32x4 Oacc[8];
#pragma unroll
  for (int i = 0; i < 8; ++i) Oacc[i] = (f32x4){0.f, 0.f, 0.f, 0.f};
  float mrun[4], lrun[4];
#pragma unroll
  for (int r = 0; r < 4; ++r) { mrun[r] = -__builtin_inff(); lrun[r] = 0.f; }

  const char* kbase = (const char*)(kws + (size_t)b * N_ * H_);
  const char* vbase = (const char*)(vtws + (size_t)b * H_ * N_);
  const int kvbase = grp * FB_KVHALF;
  char* pbase = (char*)Plds[wave];

  auto stage = [&](int buf, int step) {
    const char* ktile = kbase + (size_t)step * FB_KVSTEP * H_ * 2;
#pragma unroll
    for (int i = 0; i < 4; ++i) {
      int chunk = wave * 4 + i;
      int off = chunk * 1024 + lane * 16;
      int row = off >> 8, col = off & 255;
      gl_lds16(ktile + row * 256 + (col ^ ((row & 7) << 4)),
               (char*)Kbuf[buf] + chunk * 1024);
    }
#pragma unroll
    for (int i = 0; i < 4; ++i) {
      int chunk = wave * 4 + i;
      int h = chunk * 4 + (lane >> 4);
      int colb = (lane & 15) * 16;
      gl_lds16(vbase + (size_t)h * (N_ * 2) + (size_t)step * 256 + (colb ^ ((h & 7) << 4)),
               (char*)Vbuf[buf] + chunk * 1024);
    }
  };

  int cur = 0;
  stage(0, 0);
  __syncthreads();

  for (int step = 0; step < FB_NSTEPS; ++step) {
    if (step + 1 < FB_NSTEPS) stage(cur ^ 1, step + 1);

    const char* Kl = (const char*)Kbuf[cur];
    const char* Vl = (const char*)Vbuf[cur];

    f32x4 S[4];
#pragma unroll
    for (int ct = 0; ct < 4; ++ct) S[ct] = (f32x4){0.f, 0.f, 0.f, 0.f};
#pragma unroll
    for (int ct = 0; ct < 4; ++ct) {
      int kvrow = kvbase + ct * 16 + l15;
#pragma unroll
      for (int kc = 0; kc < 4; ++kc) {
        short8 bfrag = *(const short8*)(Kl +
            ((kvrow * 256 + (8 * l4 + 32 * kc) * 2) ^ ((kvrow & 7) << 4)));
        S[ct] = __builtin_amdgcn_mfma_f32_16x16x32_bf16(qfrag[kc], bfrag, S[ct], 0, 0, 0);
      }
    }

    float mnew[4];
#pragma unroll
    for (int r = 0; r < 4; ++r) {
      float mx = fmaxf(fmaxf(S[0][r], S[1][r]), fmaxf(S[2][r], S[3][r]));
      mx = fmaxf(mx, __shfl_xor(mx, 1));
      mx = fmaxf(mx, __shfl_xor(mx, 2));
      mx = fmaxf(mx, __shfl_xor(mx, 4));
      mx = fmaxf(mx, __shfl_xor(mx, 8));
      mnew[r] = mx;
    }
    float alpha[4];
#pragma unroll
    for (int r = 0; r < 4; ++r) {
      float mi = fmaxf(mrun[r], mnew[r]);
      alpha[r] = __builtin_amdgcn_exp2f(mrun[r] - mi);
      mrun[r] = mi;
    }
    float rsum[4] = {0.f, 0.f, 0.f, 0.f};
    unsigned short pb[4][4];
#pragma unroll
    for (int ct = 0; ct < 4; ++ct)
#pragma unroll
      for (int r = 0; r < 4; ++r) {
        float pv = __builtin_amdgcn_exp2f(S[ct][r] - mrun[r]);
        rsum[r] += pv;
        pb[ct][r] = f2bf(pv);
      }
#pragma unroll
    for (int r = 0; r < 4; ++r) {
      float s = rsum[r];
      s += __shfl_xor(s, 1); s += __shfl_xor(s, 2);
      s += __shfl_xor(s, 4); s += __shfl_xor(s, 8);
      lrun[r] = lrun[r] * alpha[r] + s;
    }
#pragma unroll
    for (int ct2 = 0; ct2 < 8; ++ct2)
#pragma unroll
      for (int r = 0; r < 4; ++r) Oacc[ct2][r] *= alpha[r];

#pragma unroll
    for (int ct = 0; ct < 4; ++ct)
#pragma unroll
      for (int r = 0; r < 4; ++r) {
        int qrow = 4 * l4 + r;
        int kv = l15 + 16 * ct;
        *(unsigned short*)(pbase + ((qrow * 128 + kv * 2) ^ ((qrow & 7) << 4))) = pb[ct][r];
      }

#pragma unroll
    for (int kc2 = 0; kc2 < 2; ++kc2) {
      short8 afrag = *(const short8*)(pbase +
          ((l15 * 128 + (8 * l4 + 32 * kc2) * 2) ^ ((l15 & 7) << 4)));
#pragma unroll
      for (int ct2 = 0; ct2 < 8; ++ct2) {
        int h = l15 + 16 * ct2;
        short8 bfrag = *(const short8*)(Vl +
            ((h * 256 + (kvbase + 8 * l4 + 32 * kc2) * 2) ^ ((h & 7) << 4)));
        Oacc[ct2] = __builtin_amdgcn_mfma_f32_16x16x32_bf16(afrag, bfrag, Oacc[ct2], 0, 0, 0);
      }
    }

    __syncthreads();
    cur ^= 1;
  }

  __syncthreads();
  float* mergeO = (float*)Kbuf;
  if (grp == 1) {
#pragma unroll
    for (int ct2 = 0; ct2 < 8; ++ct2)
#pragma unroll
      for (int r = 0; r < 4; ++r) {
        int qrow = 4 * l4 + r, h = l15 + 16 * ct2;
        mergeO[(sub * 16 + qrow) * H_ + h] = Oacc[ct2][r];
      }
    if (l15 == 0) {
#pragma unroll
      for (int r = 0; r < 4; ++r) {
        int qrow = 4 * l4 + r;
        MLlds[sub][qrow][0] = mrun[r];
        MLlds[sub][qrow][1] = lrun[r];
      }
    }
  }
  __syncthreads();
  if (grp == 0) {
    float aA[4], aB[4], rl[4];
#pragma unroll
    for (int r = 0; r < 4; ++r) {
      int qrow = 4 * l4 + r;
      float mB = MLlds[sub][qrow][0], lB = MLlds[sub][qrow][1];
      float mi = fmaxf(mrun[r], mB);
      aA[r] = __builtin_amdgcn_exp2f(mrun[r] - mi);
      aB[r] = __builtin_amdgcn_exp2f(mB - mi);
      rl[r] = 1.f / (lrun[r] * aA[r] + lB * aB[r]);
    }
    float* outp = out + ((size_t)b * N_ + qbase + sub * 16) * H_;
#pragma unroll
    for (int ct2 = 0; ct2 < 8; ++ct2)
#pragma unroll
      for (int r = 0; r < 4; ++r) {
        int qrow = 4 * l4 + r, h = l15 + 16 * ct2;
        float ob = mergeO[(sub * 16 + qrow) * H_ + h];
        outp[(size_t)qrow * H_ + h] = (Oacc[ct2][r] * aA[r] + ob * aB[r]) * rl[r];
      }
  }
}

extern "C" void kernel_launch(void* const* d_in, const int* in_sizes, int n_in,
                              void* d_out, int out_size, void* d_ws, size_t ws_size,
                              hipStream_t stream) {
  const float* q = (const float*)d_in[0];
  const float* k = (const float*)d_in[1];
  const float* v = (const float*)d_in[2];
  float* out = (float*)d_out;

  auto need = [](int ks) {
    return 3 * TSB + (size_t)ks * ELEMS * 4 + (size_t)ks * B_ * N_ * 2 * 4;
  };

  if (ws_size >= need(4)) {
    unsigned short* qb = (unsigned short*)d_ws;
    unsigned short* kb = qb + ELEMS;
    unsigned short* vt = kb + ELEMS;
    float* opart = (float*)((char*)d_ws + 3 * TSB);
    float* mlpart = opart + (size_t)4 * ELEMS;
    conv_qk<<<dim3((unsigned)(ELEMS / 8 / 256)), dim3(256), 0, stream>>>(q, k, qb, kb);
    conv_vt<<<dim3(N_ / 64, H_ / 64, B_), dim3(256), 0, stream>>>(v, vt);
    fattn_v6<4><<<dim3(512), dim3(NTH), 0, stream>>>(qb, kb, vt, opart, mlpart);
    combine_k<4><<<dim3(B_ * N_ / 8), dim3(256), 0, stream>>>(opart, mlpart, out);
  } else if (ws_size >= need(2)) {
    unsigned short* qb = (unsigned short*)d_ws;
    unsigned short* kb = qb + ELEMS;
    unsigned short* vt = kb + ELEMS;
    float* opart = (float*)((char*)d_ws + 3 * TSB);
    float* mlpart = opart + (size_t)2 * ELEMS;
    conv_qk<<<dim3((unsigned)(ELEMS / 8 / 256)), dim3(256), 0, stream>>>(q, k, qb, kb);
    conv_vt<<<dim3(N_ / 64, H_ / 64, B_), dim3(256), 0, stream>>>(v, vt);
    fattn_v6<2><<<dim3(256), dim3(NTH), 0, stream>>>(qb, kb, vt, opart, mlpart);
    combine_k<2><<<dim3(B_ * N_ / 8), dim3(256), 0, stream>>>(opart, mlpart, out);
  } else if (ws_size >= 3 * TSB) {
    unsigned short* qb = (unsigned short*)d_ws;
    unsigned short* kb = qb + ELEMS;
    unsigned short* vt = kb + ELEMS;
    conv_qk<<<dim3((unsigned)(ELEMS / 8 / 256)), dim3(256), 0, stream>>>(q, k, qb, kb);
    conv_vt<<<dim3(N_ / 64, H_ / 64, B_), dim3(256), 0, stream>>>(v, vt);
    fattn_fast<<<dim3(N_ / FB_QTILE, B_), dim3(FB_NTH), 0, stream>>>(qb, kb, vt, out);
  }
}